// Round 6
// baseline (795.114 us; speedup 1.0000x reference)
//
#include <hip/hip_runtime.h>

// ChebyshevKAN on MI355X (gfx950).
// Reformulation: einsum(bid,oid->bo) + x@base_w.T  ==  Xaug @ W^T with
//   Xaug[b, i*6+d] = T_{d+1}(tanh(x_i))  (d=0..4),  Xaug[b, i*6+5] = x_i
//   W[o,    i*6+d] = coeff[o,i,d+1]      (d=0..4),  W[o,    i*6+5] = base_w[o,i]
// T0==1 slice folds into bias:  bias'[o] = bias[o] + sum_i coeff[o,i,0].
// GEMMs run bf16 MFMA (16x16x32), fp32 accumulate; nonlinearity in fp32.
//
// R6: (1) gemm2 split-K: 128x128 tile x 2 K-halves -> grid 1024 @ 4/CU with
// gemm1's 1024 B/MFMA staging ratio (BM=64 was 1536); partials in ws (P0
// aliases dead h), deterministic reduce adds P0+P1+bias. (2) T0-bias folded
// into prep_w via block-reduce + atomicAdd (prep_bias's stride-24 pass gone).
// Verified keeps: launch_bounds(256,4) [R5: occ 30%, VGPR 56, FETCH ~ideal],
// XOR LDS swizzle [R2: conflicts 0], hoisted frag ptrs [R4], fast_tanh [R4].

typedef __bf16 bf16x8 __attribute__((ext_vector_type(8)));
typedef float f32x4 __attribute__((ext_vector_type(4)));
typedef unsigned short u16x8 __attribute__((ext_vector_type(8)));

__device__ __forceinline__ unsigned short f2bf(float f) {
    unsigned int u = __float_as_uint(f);
    unsigned int r = (u + 0x7FFFu + ((u >> 16) & 1u)) >> 16;
    return (unsigned short)r;
}
__device__ __forceinline__ float bf2f(unsigned short b) {
    return __uint_as_float(((unsigned int)b) << 16);
}

// tanh via hardware exp/rcp: err ~1e-6, way below bf16 quantization.
__device__ __forceinline__ float fast_tanh(float x) {
    float a = fminf(fmaxf(x, -15.f), 15.f);
    float e = __expf(2.f * a);
    return 1.f - 2.f * __builtin_amdgcn_rcpf(e + 1.f);
}
__device__ __forceinline__ float fast_silu(float y) {
    float a = fminf(fmaxf(y, -30.f), 30.f);
    return y * __builtin_amdgcn_rcpf(1.f + __expf(-a));
}

__device__ __forceinline__ void cheb_pack(float s, unsigned short* o6) {
    float u  = fast_tanh(s);
    float T1 = u;
    float T2 = 2.f * u * u - 1.f;
    float T3 = 2.f * u * T2 - T1;
    float T4 = 2.f * u * T3 - T2;
    float T5 = 2.f * u * T4 - T3;
    o6[0] = f2bf(T1); o6[1] = f2bf(T2); o6[2] = f2bf(T3);
    o6[3] = f2bf(T4); o6[4] = f2bf(T5); o6[5] = f2bf(s);
}

__device__ __forceinline__ void load_lds16(const void* g, void* l) {
    __builtin_amdgcn_global_load_lds(
        (const __attribute__((address_space(1))) void*)g,
        (__attribute__((address_space(3))) void*)l, 16, 0, 0);
}

// ---- prep: weights [O,I,6]+[O,I] -> W[N=O,K=I*6] bf16; T0 sums -> bp -------
// Each block covers 256 consecutive idx = 256 consecutive i within ONE o
// (I=1024 is a multiple of 256), so one atomicAdd(bp[o]) per block.
__global__ __launch_bounds__(256) void prep_w_kernel(
    const float* __restrict__ coeff, const float* __restrict__ base_w,
    unsigned short* __restrict__ W, float* __restrict__ bp)
{
    int idx = blockIdx.x * 256 + threadIdx.x;
    const float* c = coeff + (size_t)idx * 6;
    float c0 = c[0];
    unsigned short w0 = f2bf(c[1]), w1 = f2bf(c[2]), w2 = f2bf(c[3]),
                   w3 = f2bf(c[4]), w4 = f2bf(c[5]), w5 = f2bf(base_w[idx]);
    unsigned int* d = (unsigned int*)(W + (size_t)idx * 6);
    d[0] = w0 | ((unsigned int)w1 << 16);
    d[1] = w2 | ((unsigned int)w3 << 16);
    d[2] = w4 | ((unsigned int)w5 << 16);

    float s = c0;
    #pragma unroll
    for (int off = 32; off > 0; off >>= 1) s += __shfl_down(s, off);
    __shared__ float red[4];
    int lane = threadIdx.x & 63, wv = threadIdx.x >> 6;
    if (lane == 0) red[wv] = s;
    __syncthreads();
    if (threadIdx.x == 0)
        atomicAdd(&bp[(blockIdx.x * 256) >> 10],
                  red[0] + red[1] + red[2] + red[3]);
}

// ---------------- expand1: x[b,1024] -> Xaug[b,6144] bf16  (block per row) ---
__global__ __launch_bounds__(256) void expand1_kernel(
    const float* __restrict__ x, unsigned short* __restrict__ Xa)
{
    int b = blockIdx.x, tid = threadIdx.x;
    f32x4 xv = *(const f32x4*)(x + (size_t)b * 1024 + tid * 4);
    alignas(16) unsigned short ov[24];
    #pragma unroll
    for (int e = 0; e < 4; e++) cheb_pack(fast_tanh(xv[e]), ov + e * 6);
    u16x8* dst = (u16x8*)(Xa + (size_t)b * 6144 + tid * 24);
    const u16x8* src = (const u16x8*)ov;
    dst[0] = src[0]; dst[1] = src[1]; dst[2] = src[2];
}

// ------------- LN + SiLU + expand2 fused (block per row of 1024, h in bf16) --
__global__ __launch_bounds__(256) void ln_silu_expand_kernel(
    const unsigned short* __restrict__ H, const float* __restrict__ gamma,
    const float* __restrict__ beta, unsigned short* __restrict__ Xa)
{
    int b = blockIdx.x, tid = threadIdx.x;
    ushort4 hb = *(const ushort4*)(H + (size_t)b * 1024 + tid * 4);
    float hv[4] = { bf2f(hb.x), bf2f(hb.y), bf2f(hb.z), bf2f(hb.w) };
    float s1 = hv[0] + hv[1] + hv[2] + hv[3];
    float s2 = hv[0]*hv[0] + hv[1]*hv[1] + hv[2]*hv[2] + hv[3]*hv[3];
    #pragma unroll
    for (int off = 32; off > 0; off >>= 1) {
        s1 += __shfl_down(s1, off);
        s2 += __shfl_down(s2, off);
    }
    __shared__ float red[8];
    __shared__ float stats[2];
    int lane = tid & 63, wv = tid >> 6;
    if (lane == 0) { red[wv] = s1; red[4 + wv] = s2; }
    __syncthreads();
    if (tid == 0) {
        float t1 = red[0] + red[1] + red[2] + red[3];
        float t2 = red[4] + red[5] + red[6] + red[7];
        float mu = t1 * (1.f / 1024.f);
        float var = t2 * (1.f / 1024.f) - mu * mu;
        stats[0] = mu;
        stats[1] = rsqrtf(var + 1e-5f);
    }
    __syncthreads();
    float mu = stats[0], rs = stats[1];
    f32x4 g  = *(const f32x4*)(gamma + tid * 4);
    f32x4 bt = *(const f32x4*)(beta  + tid * 4);
    alignas(16) unsigned short ov[24];
    #pragma unroll
    for (int e = 0; e < 4; e++) {
        float y = (hv[e] - mu) * rs * g[e] + bt[e];
        cheb_pack(fast_silu(y), ov + e * 6);
    }
    u16x8* dst = (u16x8*)(Xa + (size_t)b * 6144 + tid * 24);
    const u16x8* src = (const u16x8*)ov;
    dst[0] = src[0]; dst[1] = src[1]; dst[2] = src[2];
}

// ---------------- bf16 GEMM: C[M,N] = A[M,K] * W[N,K]^T (+ bias) -------------
// 128x128 tile, BK=64, global_load_lds width-16 + XOR chunk swizzle
// (conflicts==0); 4 waves x 4x4 16x16x32 MFMAs; hoisted frag ptrs;
// launch_bounds(256,4) -> 4 blocks/CU. PARTIAL: grid = tiles*2, block
// (bkid&1) computes K-half into P + split*splitStride, no bias.
template<bool OUT_BF16, bool PARTIAL>
__global__ __launch_bounds__(256, 4) void gemm_kernel(
    const unsigned short* __restrict__ A,   // [M,K] bf16 bits
    const unsigned short* __restrict__ Wt,  // [N,K] bf16 bits
    const float* __restrict__ biasA,        // [N] (unused if PARTIAL)
    const float* __restrict__ biasB,        // [N] (unused if PARTIAL)
    void* __restrict__ Cout,                // [M,N] f32/bf16, or partial f32
    int N, int K, int kLen, size_t splitStride)
{
    __shared__ __align__(16) unsigned short As[128 * 64];
    __shared__ __align__(16) unsigned short Bs[128 * 64];
    const int tid  = threadIdx.x;
    const int lane = tid & 63;
    const int wave = tid >> 6;
    const int ntn  = N >> 7;

    int bkid = blockIdx.x;
    int split = 0;
    if (PARTIAL) { split = bkid & 1; bkid >>= 1; }

    // XCD-affinity swizzle (verified harmless; bijective)
    const int nm = (PARTIAL ? (gridDim.x >> 1) : gridDim.x) / ntn;
    int mt, nt;
    if ((nm & 7) == 0) {
        const int mg = nm >> 3;
        const int s  = bkid >> 3;
        const int q  = s / ntn;
        mt = (bkid & 7) * mg + q;
        nt = s - q * ntn;
    } else {
        mt = bkid / ntn; nt = bkid % ntn;
    }
    const size_t m0 = (size_t)mt << 7;
    const size_t n0 = (size_t)nt << 7;

    const int wr = (wave >> 1) * 64;
    const int wc = (wave & 1) * 64;
    const int fr = lane & 15;
    const int cg = lane >> 4;
    const int srow = tid >> 3;
    const int schunk = (tid & 7) ^ (srow & 7);

    const int fr7 = fr & 7;
    const unsigned short* fA0 = As + (wr + fr) * 64 + ((cg    ) ^ fr7) * 8;
    const unsigned short* fA1 = As + (wr + fr) * 64 + ((cg + 4) ^ fr7) * 8;
    const unsigned short* fB0 = Bs + (wc + fr) * 64 + ((cg    ) ^ fr7) * 8;
    const unsigned short* fB1 = Bs + (wc + fr) * 64 + ((cg + 4) ^ fr7) * 8;

    const unsigned short* Agu = A  + m0 * (size_t)K;
    const unsigned short* Bgu = Wt + n0 * (size_t)K;
    const int loff = srow * K + schunk * 8;

    f32x4 acc[4][4];
    #pragma unroll
    for (int i = 0; i < 4; i++)
        #pragma unroll
        for (int j = 0; j < 4; j++) acc[i][j] = f32x4{0.f, 0.f, 0.f, 0.f};

    const int kbeg = PARTIAL ? split * kLen : 0;
    const int kend = kbeg + kLen;
    for (int k0 = kbeg; k0 < kend; k0 += 64) {
        const unsigned short* ak = Agu + k0;
        const unsigned short* bk = Bgu + k0;
        #pragma unroll
        for (int s = 0; s < 4; ++s)
            load_lds16(ak + s * 32 * K + loff, &As[(s * 256 + wave * 64) * 8]);
        #pragma unroll
        for (int s = 0; s < 4; ++s)
            load_lds16(bk + s * 32 * K + loff, &Bs[(s * 256 + wave * 64) * 8]);
        __syncthreads();

        bf16x8 af[4], bfr[4];
        #pragma unroll
        for (int i = 0; i < 4; i++) af[i]  = *(const bf16x8*)(fA0 + i * 1024);
        #pragma unroll
        for (int j = 0; j < 4; j++) bfr[j] = *(const bf16x8*)(fB0 + j * 1024);
        #pragma unroll
        for (int i = 0; i < 4; i++)
            #pragma unroll
            for (int j = 0; j < 4; j++)
                acc[i][j] = __builtin_amdgcn_mfma_f32_16x16x32_bf16(
                    af[i], bfr[j], acc[i][j], 0, 0, 0);
        #pragma unroll
        for (int i = 0; i < 4; i++) af[i]  = *(const bf16x8*)(fA1 + i * 1024);
        #pragma unroll
        for (int j = 0; j < 4; j++) bfr[j] = *(const bf16x8*)(fB1 + j * 1024);
        #pragma unroll
        for (int i = 0; i < 4; i++)
            #pragma unroll
            for (int j = 0; j < 4; j++)
                acc[i][j] = __builtin_amdgcn_mfma_f32_16x16x32_bf16(
                    af[i], bfr[j], acc[i][j], 0, 0, 0);
        __syncthreads();
    }

    // C/D layout (verified m89/m91): col = lane&15, row = (lane>>4)*4 + reg
    const int rbase = wr + (lane >> 4) * 4;
    const int cbase = wc + (lane & 15);
    #pragma unroll
    for (int j = 0; j < 4; j++) {
        const int col = (int)n0 + cbase + j * 16;
        float bv = 0.f;
        if (!PARTIAL) bv = biasA[col] + biasB[col];
        #pragma unroll
        for (int i = 0; i < 4; i++) {
            #pragma unroll
            for (int r = 0; r < 4; r++) {
                const size_t idx = (m0 + rbase + i * 16 + r) * N + col;
                if (PARTIAL)
                    ((float*)Cout)[split * splitStride + idx] = acc[i][j][r];
                else if (OUT_BF16)
                    ((unsigned short*)Cout)[idx] = f2bf(acc[i][j][r] + bv);
                else
                    ((float*)Cout)[idx] = acc[i][j][r] + bv;
            }
        }
    }
}

// ---- reduce: out = P0 + P1 + biasA + biasB   (f32x4, N=512 cols) -----------
__global__ __launch_bounds__(256) void reduce_kernel(
    const float* __restrict__ P0, const float* __restrict__ P1,
    const float* __restrict__ biasA, const float* __restrict__ biasB,
    float* __restrict__ out)
{
    size_t i4 = (size_t)blockIdx.x * 256 + threadIdx.x;
    int col = ((int)(i4 & 127)) * 4;
    f32x4 a = ((const f32x4*)P0)[i4];
    f32x4 b = ((const f32x4*)P1)[i4];
    f32x4 ba = *(const f32x4*)(biasA + col);
    f32x4 bb = *(const f32x4*)(biasB + col);
    ((f32x4*)out)[i4] = a + b + ba + bb;
}

extern "C" void kernel_launch(void* const* d_in, const int* in_sizes, int n_in,
                              void* d_out, int out_size, void* d_ws, size_t ws_size,
                              hipStream_t stream)
{
    const float* x       = (const float*)d_in[0];
    const float* coeff1  = (const float*)d_in[1];
    const float* base_w1 = (const float*)d_in[2];
    const float* bias1   = (const float*)d_in[3];
    const float* gamma   = (const float*)d_in[4];
    const float* beta    = (const float*)d_in[5];
    const float* coeff2  = (const float*)d_in[6];
    const float* base_w2 = (const float*)d_in[7];
    const float* bias2   = (const float*)d_in[8];
    float* out = (float*)d_out;

    const int B = 16384, D0 = 1024, D1 = 1024, D2 = 512;
    const int K1 = D0 * 6, K2 = D1 * 6;   // 6144 each

    // workspace layout
    char* base = (char*)d_ws;
    size_t off = 0;
    unsigned short* W1 = (unsigned short*)(base + off); off += (size_t)D1 * K1 * 2;
    unsigned short* W2 = (unsigned short*)(base + off); off += (size_t)D2 * K2 * 2;
    float* b1p = (float*)(base + off); off += (size_t)D1 * 4;
    float* b2p = (float*)(base + off); off += (size_t)D2 * 4;
    off = (off + 255) & ~(size_t)255;

    // per chunk: Xa (K1 bf16) + P0 (=h alias, 512 f32) + P1 (512 f32); %128
    size_t per_row = (size_t)K1 * 2 + (size_t)D2 * 4 * 2;   // 16384 B
    long long avail = (long long)ws_size - (long long)off;
    long long mcl = avail > 0 ? avail / (long long)per_row : 0;
    int Mc = (int)((mcl / 128) * 128);
    if (Mc < 128) Mc = 128;
    if (Mc > B) Mc = B;

    unsigned short* Xa = (unsigned short*)(base + off);
    float* P0 = (float*)(base + off + (size_t)Mc * K1 * 2);  // also h (bf16)
    unsigned short* h = (unsigned short*)P0;                 // Mc*1024*2 = Mc*512*4
    const size_t splitStride = (size_t)Mc * D2;              // P1 = P0 + stride

    hipMemsetAsync(b1p, 0, (size_t)(D1 + D2) * 4, stream);
    prep_w_kernel<<<(D1 * D0) / 256, 256, 0, stream>>>(coeff1, base_w1, W1, b1p);
    prep_w_kernel<<<(D2 * D1) / 256, 256, 0, stream>>>(coeff2, base_w2, W2, b2p);

    for (int m0 = 0; m0 < B; m0 += Mc) {
        int rows = (B - m0 < Mc) ? (B - m0) : Mc;
        expand1_kernel<<<rows, 256, 0, stream>>>(x + (size_t)m0 * D0, Xa);
        gemm_kernel<true, false><<<(rows / 128) * (D1 / 128), 256, 0, stream>>>(
            Xa, W1, bias1, b1p, h, D1, K1, K1, 0);
        ln_silu_expand_kernel<<<rows, 256, 0, stream>>>(h, gamma, beta, Xa);
        gemm_kernel<false, true><<<(rows / 128) * (D2 / 128) * 2, 256, 0, stream>>>(
            Xa, W2, nullptr, nullptr, P0, D2, K2, K2 / 2, splitStride);
        reduce_kernel<<<(rows * D2) / 1024, 256, 0, stream>>>(
            P0, P0 + splitStride, bias2, b2p, out + (size_t)m0 * D2);
    }
}